// Round 13
// baseline (2450.551 us; speedup 1.0000x reference)
//
#include <hip/hip_runtime.h>

// NTM controller B=64,T=512,I=64,H=256,O=64. Memory module provably dead
// (mem0=0 -> lw=0 -> add=tanh(0)=0 -> mem stays 0, read_vec=0):
//   LSTM recurrence + out = h @ W_dec[:, :256]^T + b_dec.
//
// Laws from rounds 1-12:
//  - W_hh f16 (512 KB) must be register-file resident; scratch spill is fatal.
//  - allocator targets 65536/blockDim arch-VGPRs; only explicit asm touches AGPRs.
//  - AGPR is NOT a valid VALU dot2 source (r12 compile fail) -> v_accvgpr_read.
//  - volatile asm serializes (r9); unbatched reads stall; LICM would hoist
//    loop-invariant non-volatile reads -> batch 8 + dummy loop-variant input.
//  - 2 waves/SIMD can't hide LDS latency (r10/r11); need 4 (1024 thr, 64 VGPR).
//  - naive h layout = 4-way bank conflict (lanes 128B apart); swizzle to 4 banks.
//
// rec: 64 blocks x 1024 thr. Thread (n=tid>>2, m=tid&3) owns gate rows
// {i,f,g,o} of unit n, k-window [64m,64m+64) = 32 f16x2 pairs/row:
//   pairs 0..3   -> VGPR (4x4 = 16 regs)
//   pairs 4..31  -> AGPR (4x28 = 112), batched accvgpr_read + v_dot2
// h f16 double-buffered in LDS (1 KB total), swizzled: quad i of window m at
// uint4 index 4i+m (banks 4 apart per lane-group -> conflict-free broadcast).
// k-reduction: 2-round quad_perm DPP butterfly (VALU, no LDS). One barrier/step.
// Phase 1 (xproj): XPh[b][t][unit][4] f16 = x@W_ih^T + b_ih + b_hh (i,f,g,o).
// Phase 3 (dec):   out[b,t,:] = H[b,t,:] @ W_dec[:, :256]^T + b_dec.

typedef _Float16 f16x2 __attribute__((ext_vector_type(2)));

#define NB   64
#define TT   512
#define XP_BYTES  (67108864u)   // 64*512*1024*2
#define HD_BYTES  (16777216u)   // 64*512*256*2

__device__ unsigned char g_ntm_ws[XP_BYTES + HD_BYTES];  // fallback workspace

union U32H { unsigned int u; f16x2 h; };
union USH  { _Float16 f; unsigned short u; };
static __device__ __forceinline__ unsigned int pack2f(float a, float b) {
    U32H v; v.h = f16x2{(_Float16)a, (_Float16)b}; return v.u;
}
static __device__ __forceinline__ f16x2 up(unsigned int u) { U32H v; v.u = u; return v.h; }
static __device__ __forceinline__ unsigned short f2s(float a) { USH v; v.f = (_Float16)a; return v.u; }

__device__ __forceinline__ float sigf(float x) { return 1.0f / (1.0f + __expf(-x)); }
__device__ __forceinline__ float tanhfast(float x) {
    float e = __expf(2.0f * x);
    return 1.0f - 2.0f / (e + 1.0f);
}

#if __has_builtin(__builtin_amdgcn_fdot2)
__device__ __forceinline__ float dot2(f16x2 a, f16x2 b, float c) {
    return __builtin_amdgcn_fdot2(a, b, c, false);
}
#else
__device__ __forceinline__ float dot2(f16x2 a, f16x2 b, float c) {
    return c + (float)a.x * (float)b.x + (float)a.y * (float)b.y;
}
#endif

// 4-lane (quad) butterfly sum via DPP quad_perm: xor1 = [1,0,3,2] = 0xB1,
// xor2 = [2,3,0,1] = 0x4E. Pure VALU -- no LDS/bpermute traffic.
#if __has_builtin(__builtin_amdgcn_update_dpp)
static __device__ __forceinline__ float qsum(float x) {
    x += __int_as_float(__builtin_amdgcn_update_dpp(0, __float_as_int(x), 0xB1, 0xF, 0xF, true));
    x += __int_as_float(__builtin_amdgcn_update_dpp(0, __float_as_int(x), 0x4E, 0xF, 0xF, true));
    return x;
}
#else
static __device__ __forceinline__ float qsum(float x) {
    x += __shfl_xor(x, 1);
    x += __shfl_xor(x, 2);
    return x;
}
#endif

// batched AGPR read; dummy loop-variant SGPR input %2 blocks LICM hoisting
#define AG_READ(dst, src, tv) \
    asm("v_accvgpr_read_b32 %0, %1" : "=v"(dst) : "a"(src), "s"(tv))

// ---------------- phase 1: x-projection ----------------
// XPh[b][t][unit g][r] f16, r=0:i,1:f,2:g,3:o. Thread tid handles rows tid, tid+512.
__global__ void __attribute__((amdgpu_flat_work_group_size(512, 512)))
xproj_kernel(const float* __restrict__ x_seq, const float* __restrict__ W_ih,
             const float* __restrict__ b_ih, const float* __restrict__ b_hh,
             unsigned short* XPh)
{
    if (!XPh) XPh = (unsigned short*)g_ntm_ws;
    __shared__ unsigned int xq[128 * 32];     // 16 KB: 128 t-rows of x, f16 pairs
    const int tid = threadIdx.x;
    const int b   = blockIdx.x >> 2;
    const int q   = blockIdx.x & 3;

    {   // stage x chunk
        const float* src = x_seq + ((size_t)b * TT + (size_t)q * 128 + (tid >> 2)) * 64
                         + (tid & 3) * 16;
        unsigned int* dst = xq + (tid >> 2) * 32 + (tid & 3) * 8;
#pragma unroll
        for (int i = 0; i < 4; ++i) {
            float4 v = ((const float4*)src)[i];
            dst[2 * i]     = pack2f(v.x, v.y);
            dst[2 * i + 1] = pack2f(v.z, v.w);
        }
    }

    unsigned int w0p[32], w1p[32];            // rows tid, tid+512 as f16 pairs
    {
        const float* r0 = W_ih + (size_t)tid * 64;
        const float* r1 = W_ih + (size_t)(tid + 512) * 64;
#pragma unroll
        for (int i = 0; i < 16; ++i) {
            float4 v0 = *(const float4*)(r0 + 4 * i);
            float4 v1 = *(const float4*)(r1 + 4 * i);
            w0p[2*i] = pack2f(v0.x, v0.y); w0p[2*i+1] = pack2f(v0.z, v0.w);
            w1p[2*i] = pack2f(v1.x, v1.y); w1p[2*i+1] = pack2f(v1.z, v1.w);
        }
    }
    const float bias0 = b_ih[tid]       + b_hh[tid];
    const float bias1 = b_ih[tid + 512] + b_hh[tid + 512];
    const int   g4A   = (tid & 255) * 4 + ((tid < 256) ? 0 : 1);   // row tid -> gate i or f
    __syncthreads();

    unsigned short* outh = XPh + ((size_t)b * TT + (size_t)q * 128) * 1024;
    for (int tt = 0; tt < 128; ++tt) {
        const uint4* xr = (const uint4*)(xq + tt * 32);
        float a0 = bias0, a1 = bias1;
        float a2 = 0.f, a3 = 0.f, a4 = 0.f, a5 = 0.f, a6 = 0.f, a7 = 0.f;
#pragma unroll
        for (int i = 0; i < 8; ++i) {
            uint4 xv = xr[i];
            a0 = dot2(up(w0p[4*i]),   up(xv.x), a0);  a1 = dot2(up(w1p[4*i]),   up(xv.x), a1);
            a2 = dot2(up(w0p[4*i+1]), up(xv.y), a2);  a3 = dot2(up(w1p[4*i+1]), up(xv.y), a3);
            a4 = dot2(up(w0p[4*i+2]), up(xv.z), a4);  a5 = dot2(up(w1p[4*i+2]), up(xv.z), a5);
            a6 = dot2(up(w0p[4*i+3]), up(xv.w), a6);  a7 = dot2(up(w1p[4*i+3]), up(xv.w), a7);
        }
        const float gA = (a0 + a2) + (a4 + a6);   // row tid
        const float gB = (a1 + a3) + (a5 + a7);   // row tid+512
        outh[tt * 1024 + g4A]     = f2s(gA);
        outh[tt * 1024 + g4A + 2] = f2s(gB);      // row tid+512 = gate r+2 of same unit
    }
}

// ---------------- phase 2: recurrence ----------------
__global__ void __attribute__((amdgpu_flat_work_group_size(1024, 1024)))
ntm_rec(const float* __restrict__ W_hh,
        const unsigned short* __restrict__ XPh_in,
        unsigned short* __restrict__ Hd_in)
{
    // h, double-buffered, SWIZZLED: f16 index of unit u = ((u&63)>>3)*32 + (u>>6)*8 + (u&7)
    // => uint4 j holds window m=j&3, quad i=j>>2 (banks 4 apart across m: conflict-free).
    __shared__ _Float16 h16[2][256];

    const unsigned short* XPh = XPh_in ? XPh_in : (const unsigned short*)g_ntm_ws;
    unsigned short*       Hd  = Hd_in  ? Hd_in  : (unsigned short*)(g_ntm_ws + XP_BYTES);

    const int tid = threadIdx.x;
    const int b   = blockIdx.x;
    const int n   = tid >> 2;        // hidden unit
    const int m   = tid & 3;         // k-window: k in [64m, 64m+64)

    // ---- weights: gate rows r*256+n, window offset 64m; 32 pairs/row:
    //      pairs 0..3 -> VGPR, pairs 4..31 -> AGPR ----
    f16x2 wv[4][4];
    unsigned int wag[112];           // [r*28 + (p-4)]
#pragma unroll
    for (int r = 0; r < 4; ++r) {
        const float* rp = W_hh + (size_t)(r * 256 + n) * 256 + 64 * m;
#pragma unroll
        for (int p = 0; p < 4; ++p) {
            float2 v = *(const float2*)(rp + 2 * p);
            wv[r][p] = f16x2{(_Float16)v.x, (_Float16)v.y};
        }
#pragma unroll
        for (int p = 0; p < 28; ++p) {
            float2 v = *(const float2*)(rp + 8 + 2 * p);
            unsigned int u = pack2f(v.x, v.y);
            asm volatile("v_accvgpr_write_b32 %0, %1" : "=a"(wag[r * 28 + p]) : "v"(u));
        }
    }

    if (tid < 64) ((uint4*)h16)[tid] = make_uint4(0u, 0u, 0u, 0u);   // both buffers = 0
    float c_state = 0.f;
    __syncthreads();

    const uint2* xpb = (const uint2*)XPh + (size_t)b * TT * 256;     // [t][unit] (i,f | g,o)
    uint4*       Hd4 = (uint4*)Hd + (size_t)b * TT * 32;

    uint2 xc = xpb[n];                                               // t = 0

    for (int t = 0; t < TT; ++t) {
        const uint4* hb = (const uint4*)h16[t & 1];
        uint2 xn = xc;
        if (t + 1 < TT) xn = xpb[(size_t)(t + 1) * 256 + n];         // prefetch

        float a0, a1, a2, a3;                                        // gates i,f,g,o
        {   // ---- quad 0: VGPR weights (pairs 0..3) ----
            const uint4 hv = hb[m];                                  // swz index 4*0+m
            a0 = dot2(wv[0][0], up(hv.x), 0.f); a0 = dot2(wv[0][1], up(hv.y), a0);
            a0 = dot2(wv[0][2], up(hv.z), a0);  a0 = dot2(wv[0][3], up(hv.w), a0);
            a1 = dot2(wv[1][0], up(hv.x), 0.f); a1 = dot2(wv[1][1], up(hv.y), a1);
            a1 = dot2(wv[1][2], up(hv.z), a1);  a1 = dot2(wv[1][3], up(hv.w), a1);
            a2 = dot2(wv[2][0], up(hv.x), 0.f); a2 = dot2(wv[2][1], up(hv.y), a2);
            a2 = dot2(wv[2][2], up(hv.z), a2);  a2 = dot2(wv[2][3], up(hv.w), a2);
            a3 = dot2(wv[3][0], up(hv.x), 0.f); a3 = dot2(wv[3][1], up(hv.y), a3);
            a3 = dot2(wv[3][2], up(hv.z), a3);  a3 = dot2(wv[3][3], up(hv.w), a3);
        }
        // ---- quads 1..7: AGPR weights (pairs 4..31), batched 8 reads + 8 dot2 ----
#pragma unroll
        for (int i = 1; i < 8; ++i) {
            const uint4 hv = hb[4 * i + m];                          // swz: conflict-free
            const int base = 4 * i - 4;                              // pair offset - 4
            unsigned int t0, t1, t2, t3, t4, t5, t6, t7;
            AG_READ(t0, wag[0 * 28 + base],     t);  AG_READ(t1, wag[0 * 28 + base + 1], t);
            AG_READ(t2, wag[1 * 28 + base],     t);  AG_READ(t3, wag[1 * 28 + base + 1], t);
            AG_READ(t4, wag[2 * 28 + base],     t);  AG_READ(t5, wag[2 * 28 + base + 1], t);
            AG_READ(t6, wag[3 * 28 + base],     t);  AG_READ(t7, wag[3 * 28 + base + 1], t);
            a0 = dot2(up(t0), up(hv.x), a0);  a0 = dot2(up(t1), up(hv.y), a0);
            a1 = dot2(up(t2), up(hv.x), a1);  a1 = dot2(up(t3), up(hv.y), a1);
            a2 = dot2(up(t4), up(hv.x), a2);  a2 = dot2(up(t5), up(hv.y), a2);
            a3 = dot2(up(t6), up(hv.x), a3);  a3 = dot2(up(t7), up(hv.y), a3);
            AG_READ(t0, wag[0 * 28 + base + 2], t);  AG_READ(t1, wag[0 * 28 + base + 3], t);
            AG_READ(t2, wag[1 * 28 + base + 2], t);  AG_READ(t3, wag[1 * 28 + base + 3], t);
            AG_READ(t4, wag[2 * 28 + base + 2], t);  AG_READ(t5, wag[2 * 28 + base + 3], t);
            AG_READ(t6, wag[3 * 28 + base + 2], t);  AG_READ(t7, wag[3 * 28 + base + 3], t);
            a0 = dot2(up(t0), up(hv.z), a0);  a0 = dot2(up(t1), up(hv.w), a0);
            a1 = dot2(up(t2), up(hv.z), a1);  a1 = dot2(up(t3), up(hv.w), a1);
            a2 = dot2(up(t4), up(hv.z), a2);  a2 = dot2(up(t5), up(hv.w), a2);
            a3 = dot2(up(t6), up(hv.z), a3);  a3 = dot2(up(t7), up(hv.w), a3);
        }

        // ---- DPP butterfly over the 4-lane group (k-windows) ----
        a0 = qsum(a0); a1 = qsum(a1); a2 = qsum(a2); a3 = qsum(a3);

        // ---- x-projection (+biases) ONCE post-reduction; LSTM cell for unit n ----
        const f16x2 lo = up(xc.x), hi = up(xc.y);
        const float gi = a0 + (float)lo.x;
        const float gf = a1 + (float)lo.y;
        const float gg = a2 + (float)hi.x;
        const float go = a3 + (float)hi.y;
        c_state = sigf(gf) * c_state + sigf(gi) * tanhfast(gg);
        const float hn = sigf(go) * tanhfast(c_state);

        _Float16* hw = h16[(t + 1) & 1];
        if (m == 0) hw[((n & 63) >> 3) * 32 + (n >> 6) * 8 + (n & 7)] = (_Float16)hn;
        __syncthreads();                                             // h_t published
        // Hd linear store: linear uint4 j (units 8j..8j+7) = swz uint4 4*(j&7)+(j>>3)
        if (tid < 32) Hd4[(size_t)t * 32 + tid] = ((const uint4*)hw)[4 * (tid & 7) + (tid >> 3)];
        xc = xn;
    }
}

// ---------------- phase 3: decode ----------------
// out[b,t,o] = b_dec[o] + H[b,t,:256] . W_dec[o,:256]
__global__ void __attribute__((amdgpu_flat_work_group_size(256, 256)))
dec_kernel(const unsigned short* __restrict__ Hd_in,
           const float* __restrict__ W_dec, const float* __restrict__ b_dec,
           float* __restrict__ out)
{
    const unsigned short* Hd = Hd_in ? Hd_in : (const unsigned short*)(g_ntm_ws + XP_BYTES);
    __shared__ unsigned int wdl[64 * 132];    // W_dec pairs, padded stride 132
    __shared__ uint4 ht[32 * 32];             // 32 t-rows x 256 f16

    const int tid = threadIdx.x;
    const int b = blockIdx.x >> 2, q = blockIdx.x & 3;

    for (int idx = tid; idx < 64 * 128; idx += 256) {
        const int o = idx >> 7, pp = idx & 127;
        wdl[o * 132 + pp] = pack2f(W_dec[(size_t)o * 384 + 2 * pp],
                                   W_dec[(size_t)o * 384 + 2 * pp + 1]);
    }
    const int o = tid & 63, tq = tid >> 6;
    const float bd = b_dec[o];
    const uint4* Hdb  = (const uint4*)Hd + ((size_t)b * TT + (size_t)q * 128) * 32;
    float*       outb = out + ((size_t)b * TT + (size_t)q * 128) * 64;

    for (int s = 0; s < 4; ++s) {
        __syncthreads();
#pragma unroll
        for (int i = 0; i < 4; ++i) {
            const int idx = tid + 256 * i;                 // 1024 uint4 = 32 rows
            ht[idx] = Hdb[s * 1024 + idx];
        }
        __syncthreads();

        float acc[8];
#pragma unroll
        for (int j = 0; j < 8; ++j) acc[j] = 0.f;

#pragma unroll
        for (int c = 0; c < 8; ++c) {                      // k-chunks of 32 slices
            uint4 w0, w1, w2, w3;
            {
                const unsigned int* wp = wdl + o * 132 + 16 * c;
                w0 = make_uint4(wp[0],  wp[1],  wp[2],  wp[3]);
                w1 = make_uint4(wp[4],  wp[5],  wp[6],  wp[7]);
                w2 = make_uint4(wp[8],  wp[9],  wp[10], wp[11]);
                w3 = make_uint4(wp[12], wp[13], wp[14], wp[15]);
            }
#pragma unroll
            for (int j = 0; j < 8; ++j) {
                const uint4* hr = &ht[(tq * 8 + j) * 32 + 4 * c];
                const uint4 h0 = hr[0], h1 = hr[1], h2 = hr[2], h3 = hr[3];
                float d = acc[j];
                d = dot2(up(w0.x), up(h0.x), d); d = dot2(up(w0.y), up(h0.y), d);
                d = dot2(up(w0.z), up(h0.z), d); d = dot2(up(w0.w), up(h0.w), d);
                d = dot2(up(w1.x), up(h1.x), d); d = dot2(up(w1.y), up(h1.y), d);
                d = dot2(up(w1.z), up(h1.z), d); d = dot2(up(w1.w), up(h1.w), d);
                d = dot2(up(w2.x), up(h2.x), d); d = dot2(up(w2.y), up(h2.y), d);
                d = dot2(up(w2.z), up(h2.z), d); d = dot2(up(w2.w), up(h2.w), d);
                d = dot2(up(w3.x), up(h3.x), d); d = dot2(up(w3.y), up(h3.y), d);
                d = dot2(up(w3.z), up(h3.z), d); d = dot2(up(w3.w), up(h3.w), d);
                acc[j] = d;
            }
        }
#pragma unroll
        for (int j = 0; j < 8; ++j)
            outb[(size_t)(s * 32 + tq * 8 + j) * 64 + o] = acc[j] + bd;
    }
}

extern "C" void kernel_launch(void* const* d_in, const int* in_sizes, int n_in,
                              void* d_out, int out_size, void* d_ws, size_t ws_size,
                              hipStream_t stream) {
    const float* x_seq = (const float*)d_in[0];
    const float* W_ih  = (const float*)d_in[1];
    const float* W_hh  = (const float*)d_in[2];
    const float* b_ih  = (const float*)d_in[3];
    const float* b_hh  = (const float*)d_in[4];
    // d_in[5..8] unused: mem == 0 forever
    const float* W_dec = (const float*)d_in[9];
    const float* b_dec = (const float*)d_in[10];
    float* out = (float*)d_out;

    unsigned short* XPh = nullptr;   // null -> kernels fall back to g_ntm_ws
    unsigned short* Hd  = nullptr;
    if (ws_size >= (size_t)XP_BYTES + HD_BYTES) {
        XPh = (unsigned short*)d_ws;
        Hd  = (unsigned short*)((unsigned char*)d_ws + XP_BYTES);
    }

    hipLaunchKernelGGL(xproj_kernel, dim3(256), dim3(512), 0, stream,
                       x_seq, W_ih, b_ih, b_hh, XPh);

    hipLaunchKernelGGL(ntm_rec, dim3(NB), dim3(1024), 0, stream,
                       W_hh, XPh, Hd);

    hipLaunchKernelGGL(dec_kernel, dim3(256), dim3(256), 0, stream,
                       Hd, W_dec, b_dec, out);
}

// Round 15
// 1988.244 us; speedup vs baseline: 1.2325x; 1.2325x over previous
//
#include <hip/hip_runtime.h>

// NTM controller B=64,T=512,I=64,H=256,O=64. Memory module provably dead
// (mem0=0 -> lw=0 -> add=tanh(0)=0 -> mem stays 0, read_vec=0):
//   LSTM recurrence + out = h @ W_dec[:, :256]^T + b_dec.
//
// MFMA path (r14) returned absmax 1.4e-2 (28x f16 floor): the inline-asm
// AGPR MFMAs (s=2..5) are the only component the compiler cannot schedule
// hazards for -> small systematic gate error integrated by the recurrence.
// r15: BUILTINS ONLY. All non-LDS B-frags in one bw[96] array; gfx950's
// unified-file allocator places MFMA B operands in AGPRs under pressure
// (demand ~478 of 512 unified regs @ 1 wave/SIMD). Compiler owns all hazards.
//
// rec: 64 blocks x 256 thr (4 waves). Wave w covers gate rows [256w,256w+256).
// Per step: 128 mfma_f32_16x16x32_f16 per wave.
//   A-frag: h slice, row 0 only (lanes l%16==0 hold h[32s+8q..+8], rest 0).
//   B-frag (g,s): lane l elem e = W[256w+16g+(l%16)][32s+8(l/16)+e] (f16).
//     s 0..5 -> bw[96] registers (VGPR+AGPR, allocator-managed);
//     s 6..7 -> LDS [w][g][s-6][lane], 16B/lane contiguous (128 KB).
//   D row0 = lanes 0-15 reg0 (m89-verified layout) -> gate_lds -> per-thread cell.
// 2 barriers/step; h f16 single-buffered (all reads precede bar[1], write after).
// Phase 1 (xproj): XPh[b][t][unit][4] f16 = x@W_ih^T + b_ih + b_hh (i,f,g,o).
// Phase 3 (dec):   out[b,t,:] = H[b,t,:] @ W_dec[:, :256]^T + b_dec.

typedef _Float16 f16x2 __attribute__((ext_vector_type(2)));
typedef _Float16 h8 __attribute__((ext_vector_type(8)));
typedef float f4 __attribute__((ext_vector_type(4)));

#define NB   64
#define TT   512
#define XP_BYTES  (67108864u)   // 64*512*1024*2
#define HD_BYTES  (16777216u)   // 64*512*256*2

__device__ unsigned char g_ntm_ws[XP_BYTES + HD_BYTES];  // fallback workspace

union U32H { unsigned int u; f16x2 h; };
union USH  { _Float16 f; unsigned short u; };
static __device__ __forceinline__ unsigned int pack2f(float a, float b) {
    U32H v; v.h = f16x2{(_Float16)a, (_Float16)b}; return v.u;
}
static __device__ __forceinline__ f16x2 up(unsigned int u) { U32H v; v.u = u; return v.h; }
static __device__ __forceinline__ unsigned short f2s(float a) { USH v; v.f = (_Float16)a; return v.u; }

__device__ __forceinline__ float sigf(float x) { return 1.0f / (1.0f + __expf(-x)); }
__device__ __forceinline__ float tanhfast(float x) {
    float e = __expf(2.0f * x);
    return 1.0f - 2.0f / (e + 1.0f);
}

#if __has_builtin(__builtin_amdgcn_fdot2)
__device__ __forceinline__ float dot2(f16x2 a, f16x2 b, float c) {
    return __builtin_amdgcn_fdot2(a, b, c, false);
}
#else
__device__ __forceinline__ float dot2(f16x2 a, f16x2 b, float c) {
    return c + (float)a.x * (float)b.x + (float)a.y * (float)b.y;
}
#endif

// builtin MFMA only: compiler manages hazards, scheduling, and AGPR placement.
static __device__ __forceinline__ f4 mfma_b(h8 a, h8 b, f4 c) {
    return __builtin_amdgcn_mfma_f32_16x16x32_f16(a, b, c, 0, 0, 0);
}

// ---------------- phase 1: x-projection ----------------
// XPh[b][t][unit g][r] f16, r=0:i,1:f,2:g,3:o. Thread tid handles rows tid, tid+512.
__global__ void __attribute__((amdgpu_flat_work_group_size(512, 512)))
xproj_kernel(const float* __restrict__ x_seq, const float* __restrict__ W_ih,
             const float* __restrict__ b_ih, const float* __restrict__ b_hh,
             unsigned short* XPh)
{
    if (!XPh) XPh = (unsigned short*)g_ntm_ws;
    __shared__ unsigned int xq[128 * 32];     // 16 KB: 128 t-rows of x, f16 pairs
    const int tid = threadIdx.x;
    const int b   = blockIdx.x >> 2;
    const int q   = blockIdx.x & 3;

    {   // stage x chunk
        const float* src = x_seq + ((size_t)b * TT + (size_t)q * 128 + (tid >> 2)) * 64
                         + (tid & 3) * 16;
        unsigned int* dst = xq + (tid >> 2) * 32 + (tid & 3) * 8;
#pragma unroll
        for (int i = 0; i < 4; ++i) {
            float4 v = ((const float4*)src)[i];
            dst[2 * i]     = pack2f(v.x, v.y);
            dst[2 * i + 1] = pack2f(v.z, v.w);
        }
    }

    unsigned int w0p[32], w1p[32];            // rows tid, tid+512 as f16 pairs
    {
        const float* r0 = W_ih + (size_t)tid * 64;
        const float* r1 = W_ih + (size_t)(tid + 512) * 64;
#pragma unroll
        for (int i = 0; i < 16; ++i) {
            float4 v0 = *(const float4*)(r0 + 4 * i);
            float4 v1 = *(const float4*)(r1 + 4 * i);
            w0p[2*i] = pack2f(v0.x, v0.y); w0p[2*i+1] = pack2f(v0.z, v0.w);
            w1p[2*i] = pack2f(v1.x, v1.y); w1p[2*i+1] = pack2f(v1.z, v1.w);
        }
    }
    const float bias0 = b_ih[tid]       + b_hh[tid];
    const float bias1 = b_ih[tid + 512] + b_hh[tid + 512];
    const int   g4A   = (tid & 255) * 4 + ((tid < 256) ? 0 : 1);   // row tid -> gate i or f
    __syncthreads();

    unsigned short* outh = XPh + ((size_t)b * TT + (size_t)q * 128) * 1024;
    for (int tt = 0; tt < 128; ++tt) {
        const uint4* xr = (const uint4*)(xq + tt * 32);
        float a0 = bias0, a1 = bias1;
        float a2 = 0.f, a3 = 0.f, a4 = 0.f, a5 = 0.f, a6 = 0.f, a7 = 0.f;
#pragma unroll
        for (int i = 0; i < 8; ++i) {
            uint4 xv = xr[i];
            a0 = dot2(up(w0p[4*i]),   up(xv.x), a0);  a1 = dot2(up(w1p[4*i]),   up(xv.x), a1);
            a2 = dot2(up(w0p[4*i+1]), up(xv.y), a2);  a3 = dot2(up(w1p[4*i+1]), up(xv.y), a3);
            a4 = dot2(up(w0p[4*i+2]), up(xv.z), a4);  a5 = dot2(up(w1p[4*i+2]), up(xv.z), a5);
            a6 = dot2(up(w0p[4*i+3]), up(xv.w), a6);  a7 = dot2(up(w1p[4*i+3]), up(xv.w), a7);
        }
        const float gA = (a0 + a2) + (a4 + a6);   // row tid
        const float gB = (a1 + a3) + (a5 + a7);   // row tid+512
        outh[tt * 1024 + g4A]     = f2s(gA);
        outh[tt * 1024 + g4A + 2] = f2s(gB);      // row tid+512 = gate r+2 of same unit
    }
}

// ---------------- phase 2: recurrence (MFMA, builtins only) ----------------
// LDS: blds h8[4w][16g][2][64 lanes] (131072 B) | gate_lds float[1024] (4096 B)
//    | h16 _Float16[256] (512 B)  => 135680 B
__global__ void __attribute__((amdgpu_flat_work_group_size(256, 256)))
ntm_rec(const float* __restrict__ W_hh,
        const unsigned short* __restrict__ XPh_in,
        unsigned short* __restrict__ Hd_in)
{
    extern __shared__ char smem[];
    h8*       blds     = (h8*)smem;                         // [ (w*16+g)*2 + s6 ][lane]
    float*    gate_lds = (float*)(smem + 131072);           // [1024]
    _Float16* h16      = (_Float16*)(smem + 131072 + 4096); // [256]

    const unsigned short* XPh = XPh_in ? XPh_in : (const unsigned short*)g_ntm_ws;
    unsigned short*       Hd  = Hd_in  ? Hd_in  : (unsigned short*)(g_ntm_ws + XP_BYTES);

    const int tid  = threadIdx.x;
    const int lane = tid & 63, w = tid >> 6;
    const int jj   = lane & 15, q = lane >> 4;
    const int b    = blockIdx.x;

    // ---- load B-fragments. Wave w covers gate rows [256w, 256w+256).
    //      frag(g,s): lane elem e = W[256w+16g+jj][32s+8q+e]  (row-major, 32B load)
    //      s 0..5 -> bw[96] (allocator splits across VGPR+AGPR); s 6..7 -> LDS.
    h8 bw[96];
#pragma unroll
    for (int g = 0; g < 16; ++g) {
        const float* rb = W_hh + (size_t)(256 * w + 16 * g + jj) * 256 + 8 * q;
#pragma unroll
        for (int s = 0; s < 8; ++s) {
            const float* src = rb + 32 * s;
            float4 x0 = *(const float4*)src;
            float4 x1 = *(const float4*)(src + 4);
            h8 f;
            f[0] = (_Float16)x0.x; f[1] = (_Float16)x0.y;
            f[2] = (_Float16)x0.z; f[3] = (_Float16)x0.w;
            f[4] = (_Float16)x1.x; f[5] = (_Float16)x1.y;
            f[6] = (_Float16)x1.z; f[7] = (_Float16)x1.w;
            if (s < 6) bw[g * 6 + s] = f;
            else       blds[((w * 16 + g) * 2 + (s - 6)) * 64 + lane] = f;
        }
    }

    if (tid < 32) ((uint4*)h16)[tid] = make_uint4(0u, 0u, 0u, 0u);   // h_0 = 0
    float c_state = 0.f;
    __syncthreads();

    const uint2* xpb = (const uint2*)XPh + (size_t)b * TT * 256;     // [t][unit] (i,f | g,o)
    uint4*       Hd4 = (uint4*)Hd + (size_t)b * TT * 32;

    uint2 xc = xpb[tid];                                             // t = 0 (unit tid)

    for (int t = 0; t < TT; ++t) {
        uint2 xn = xc;
        if (t + 1 < TT) xn = xpb[(size_t)(t + 1) * 256 + tid];       // prefetch

        f4 cacc[16];
#pragma unroll
        for (int g = 0; g < 16; ++g) cacc[g] = f4{0.f, 0.f, 0.f, 0.f};

        // ---- 8 k-slices; per slice: A-frag (h in row 0 only) + 16 group MFMAs ----
#pragma unroll
        for (int s = 0; s < 8; ++s) {
            h8 af = {};
            if (jj == 0) af = *(const h8*)(h16 + s * 32 + q * 8);
            if (s < 6) {
#pragma unroll
                for (int g = 0; g < 16; ++g)
                    cacc[g] = mfma_b(af, bw[g * 6 + s], cacc[g]);
            } else {
#pragma unroll
                for (int g = 0; g < 16; ++g) {
                    h8 bb = blds[((w * 16 + g) * 2 + (s - 6)) * 64 + lane];
                    cacc[g] = mfma_b(af, bb, cacc[g]);
                }
            }
        }

        // ---- D row 0 = lanes 0-15, reg 0: gate[256w + 16g + lane] ----
        if (lane < 16) {
#pragma unroll
            for (int g = 0; g < 16; ++g)
                gate_lds[w * 256 + g * 16 + lane] = cacc[g][0];
        }
        __syncthreads();                      // [1] gates visible to all waves

        // ---- cell: thread u = tid handles unit u ----
        {
            const f16x2 lo = up(xc.x), hi = up(xc.y);
            const float gi = gate_lds[tid]       + (float)lo.x;
            const float gf = gate_lds[256 + tid] + (float)lo.y;
            const float gg = gate_lds[512 + tid] + (float)hi.x;
            const float go = gate_lds[768 + tid] + (float)hi.y;
            c_state = sigf(gf) * c_state + sigf(gi) * tanhfast(gg);
            const float hn = sigf(go) * tanhfast(c_state);
            h16[tid] = (_Float16)hn;
        }
        __syncthreads();                      // [2] h_t published

        if (tid < 32) Hd4[(size_t)t * 32 + tid] = ((const uint4*)h16)[tid];
        xc = xn;
    }
}

// ---------------- phase 3: decode ----------------
// out[b,t,o] = b_dec[o] + H[b,t,:256] . W_dec[o,:256]
__global__ void __attribute__((amdgpu_flat_work_group_size(256, 256)))
dec_kernel(const unsigned short* __restrict__ Hd_in,
           const float* __restrict__ W_dec, const float* __restrict__ b_dec,
           float* __restrict__ out)
{
    const unsigned short* Hd = Hd_in ? Hd_in : (const unsigned short*)(g_ntm_ws + XP_BYTES);
    __shared__ unsigned int wdl[64 * 132];    // W_dec pairs, padded stride 132
    __shared__ uint4 ht[32 * 32];             // 32 t-rows x 256 f16

    const int tid = threadIdx.x;
    const int b = blockIdx.x >> 2, q = blockIdx.x & 3;

    for (int idx = tid; idx < 64 * 128; idx += 256) {
        const int o = idx >> 7, pp = idx & 127;
        wdl[o * 132 + pp] = pack2f(W_dec[(size_t)o * 384 + 2 * pp],
                                   W_dec[(size_t)o * 384 + 2 * pp + 1]);
    }
    const int o = tid & 63, tq = tid >> 6;
    const float bd = b_dec[o];
    const uint4* Hdb  = (const uint4*)Hd + ((size_t)b * TT + (size_t)q * 128) * 32;
    float*       outb = out + ((size_t)b * TT + (size_t)q * 128) * 64;

    for (int s = 0; s < 4; ++s) {
        __syncthreads();
#pragma unroll
        for (int i = 0; i < 4; ++i) {
            const int idx = tid + 256 * i;                 // 1024 uint4 = 32 rows
            ht[idx] = Hdb[s * 1024 + idx];
        }
        __syncthreads();

        float acc[8];
#pragma unroll
        for (int j = 0; j < 8; ++j) acc[j] = 0.f;

#pragma unroll
        for (int c = 0; c < 8; ++c) {                      // k-chunks of 32 slices
            uint4 w0, w1, w2, w3;
            {
                const unsigned int* wp = wdl + o * 132 + 16 * c;
                w0 = make_uint4(wp[0],  wp[1],  wp[2],  wp[3]);
                w1 = make_uint4(wp[4],  wp[5],  wp[6],  wp[7]);
                w2 = make_uint4(wp[8],  wp[9],  wp[10], wp[11]);
                w3 = make_uint4(wp[12], wp[13], wp[14], wp[15]);
            }
#pragma unroll
            for (int j = 0; j < 8; ++j) {
                const uint4* hr = &ht[(tq * 8 + j) * 32 + 4 * c];
                const uint4 h0 = hr[0], h1 = hr[1], h2 = hr[2], h3 = hr[3];
                float d = acc[j];
                d = dot2(up(w0.x), up(h0.x), d); d = dot2(up(w0.y), up(h0.y), d);
                d = dot2(up(w0.z), up(h0.z), d); d = dot2(up(w0.w), up(h0.w), d);
                d = dot2(up(w1.x), up(h1.x), d); d = dot2(up(w1.y), up(h1.y), d);
                d = dot2(up(w1.z), up(h1.z), d); d = dot2(up(w1.w), up(h1.w), d);
                d = dot2(up(w2.x), up(h2.x), d); d = dot2(up(w2.y), up(h2.y), d);
                d = dot2(up(w2.z), up(h2.z), d); d = dot2(up(w2.w), up(h2.w), d);
                d = dot2(up(w3.x), up(h3.x), d); d = dot2(up(w3.y), up(h3.y), d);
                d = dot2(up(w3.z), up(h3.z), d); d = dot2(up(w3.w), up(h3.w), d);
                acc[j] = d;
            }
        }
#pragma unroll
        for (int j = 0; j < 8; ++j)
            outb[(size_t)(s * 32 + tq * 8 + j) * 64 + o] = acc[j] + bd;
    }
}

extern "C" void kernel_launch(void* const* d_in, const int* in_sizes, int n_in,
                              void* d_out, int out_size, void* d_ws, size_t ws_size,
                              hipStream_t stream) {
    const float* x_seq = (const float*)d_in[0];
    const float* W_ih  = (const float*)d_in[1];
    const float* W_hh  = (const float*)d_in[2];
    const float* b_ih  = (const float*)d_in[3];
    const float* b_hh  = (const float*)d_in[4];
    // d_in[5..8] unused: mem == 0 forever
    const float* W_dec = (const float*)d_in[9];
    const float* b_dec = (const float*)d_in[10];
    float* out = (float*)d_out;

    unsigned short* XPh = nullptr;   // null -> kernels fall back to g_ntm_ws
    unsigned short* Hd  = nullptr;
    if (ws_size >= (size_t)XP_BYTES + HD_BYTES) {
        XPh = (unsigned short*)d_ws;
        Hd  = (unsigned short*)((unsigned char*)d_ws + XP_BYTES);
    }

    hipLaunchKernelGGL(xproj_kernel, dim3(256), dim3(512), 0, stream,
                       x_seq, W_ih, b_ih, b_hh, XPh);

    const size_t smem_rec = 131072 + 4096 + 512;   // 135680 B
    hipFuncSetAttribute((const void*)&ntm_rec,
                        hipFuncAttributeMaxDynamicSharedMemorySize, (int)smem_rec);
    hipLaunchKernelGGL(ntm_rec, dim3(NB), dim3(256), smem_rec, stream,
                       W_hh, XPh, Hd);

    hipLaunchKernelGGL(dec_kernel, dim3(256), dim3(256), 0, stream,
                       Hd, W_dec, b_dec, out);
}

// Round 16
// 1877.540 us; speedup vs baseline: 1.3052x; 1.0590x over previous
//
#include <hip/hip_runtime.h>

// NTM controller B=64,T=512,I=64,H=256,O=64. Memory module provably dead
// (mem0=0 -> lw=0 -> add=tanh(0)=0 -> mem stays 0, read_vec=0):
//   LSTM recurrence + out = h @ W_dec[:, :256]^T + b_dec.
//
// Laws (rounds 1-15): register file/CU (512KB) == |W_hh f16| -> full residency is
// impossible with working state. Best measured structure = r8: VALU pipe saturated
// by dot2 while the MEMORY pipe streams the overflow (compiler scratch spill).
// This round replaces the spill machinery with an explicit streamed tier:
//   per gate row (128 f16x2 pairs), quad-aligned tiers:
//     pairs  0..19  -> VGPR (80 regs; total demand ~110 < 128 => NO spill)
//     pairs 20..55  -> LDS [18][512] uint4 (147456 B, 16B/lane conflict-free)
//     pairs 56..127 -> streamed: packed global WS [36 quads][512 thr] uint4
//                      (288 KB, shared by all blocks -> L2/L3 resident, coalesced)
// rec: 64 blocks x 512 thr (2 waves/SIMD). Thread (u=tid>>1, e=tid&1) owns rows
// {u+512e, 256+u+512e}. Gate exchange = shfl_xor lane^1. 1 barrier/step,
// h f16 double-buffered in LDS. Stream tier consumed FIRST (memory-early),
// VGPR tier last (pure VALU covers load tails).
// Phase 0 (pack): WS built from W_hh (36 blocks).
// Phase 1 (xproj): XPh[b][t][unit][4] f16 = x@W_ih^T + b_ih + b_hh (i,f,g,o).
// Phase 3 (dec):   out[b,t,:] = H[b,t,:] @ W_dec[:, :256]^T + b_dec.

typedef _Float16 f16x2 __attribute__((ext_vector_type(2)));

#define NB   64
#define TT   512
#define XP_BYTES  (67108864u)   // 64*512*1024*2
#define HD_BYTES  (16777216u)   // 64*512*256*2
#define WS_BYTES  (294912u)     // 36*512*16

__device__ unsigned char g_ntm_ws[XP_BYTES + HD_BYTES + WS_BYTES];  // fallback

union U32H { unsigned int u; f16x2 h; };
union USH  { _Float16 f; unsigned short u; };
static __device__ __forceinline__ unsigned int pack2f(float a, float b) {
    U32H v; v.h = f16x2{(_Float16)a, (_Float16)b}; return v.u;
}
static __device__ __forceinline__ f16x2 up(unsigned int u) { U32H v; v.u = u; return v.h; }
static __device__ __forceinline__ unsigned short f2s(float a) { USH v; v.f = (_Float16)a; return v.u; }

__device__ __forceinline__ float sigf(float x) { return 1.0f / (1.0f + __expf(-x)); }
__device__ __forceinline__ float tanhfast(float x) {
    float e = __expf(2.0f * x);
    return 1.0f - 2.0f / (e + 1.0f);
}

#if __has_builtin(__builtin_amdgcn_fdot2)
__device__ __forceinline__ float dot2(f16x2 a, f16x2 b, float c) {
    return __builtin_amdgcn_fdot2(a, b, c, false);
}
#else
__device__ __forceinline__ float dot2(f16x2 a, f16x2 b, float c) {
    return c + (float)a.x * (float)b.x + (float)a.y * (float)b.y;
}
#endif

// ---------------- phase 0: pack streamed weight tier ----------------
// WS[s][tid] (uint4): s even -> row u+512e, s odd -> row 256+u+512e; quad 14+(s>>1)
// (pairs 56..127). Same data consumed by every rec block.
__global__ void __attribute__((amdgpu_flat_work_group_size(512, 512)))
pack_kernel(const float* __restrict__ W_hh, unsigned int* WSu)
{
    if (!WSu) WSu = (unsigned int*)(g_ntm_ws + XP_BYTES + HD_BYTES);
    const int s   = blockIdx.x;          // 0..35
    const int tid = threadIdx.x;
    const int u = tid >> 1, e = tid & 1;
    const int row = (s & 1) ? (256 + u + 512 * e) : (u + 512 * e);
    const int qA  = 14 + (s >> 1);
    const float* rp = W_hh + (size_t)row * 256 + 8 * qA;
    uint4 v;
    v.x = pack2f(rp[0], rp[1]); v.y = pack2f(rp[2], rp[3]);
    v.z = pack2f(rp[4], rp[5]); v.w = pack2f(rp[6], rp[7]);
    ((uint4*)WSu)[s * 512 + tid] = v;
}

// ---------------- phase 1: x-projection ----------------
// XPh[b][t][unit g][r] f16, r=0:i,1:f,2:g,3:o. Thread tid handles rows tid, tid+512.
__global__ void __attribute__((amdgpu_flat_work_group_size(512, 512)))
xproj_kernel(const float* __restrict__ x_seq, const float* __restrict__ W_ih,
             const float* __restrict__ b_ih, const float* __restrict__ b_hh,
             unsigned short* XPh)
{
    if (!XPh) XPh = (unsigned short*)g_ntm_ws;
    __shared__ unsigned int xq[128 * 32];     // 16 KB: 128 t-rows of x, f16 pairs
    const int tid = threadIdx.x;
    const int b   = blockIdx.x >> 2;
    const int q   = blockIdx.x & 3;

    {   // stage x chunk
        const float* src = x_seq + ((size_t)b * TT + (size_t)q * 128 + (tid >> 2)) * 64
                         + (tid & 3) * 16;
        unsigned int* dst = xq + (tid >> 2) * 32 + (tid & 3) * 8;
#pragma unroll
        for (int i = 0; i < 4; ++i) {
            float4 v = ((const float4*)src)[i];
            dst[2 * i]     = pack2f(v.x, v.y);
            dst[2 * i + 1] = pack2f(v.z, v.w);
        }
    }

    unsigned int w0p[32], w1p[32];            // rows tid, tid+512 as f16 pairs
    {
        const float* r0 = W_ih + (size_t)tid * 64;
        const float* r1 = W_ih + (size_t)(tid + 512) * 64;
#pragma unroll
        for (int i = 0; i < 16; ++i) {
            float4 v0 = *(const float4*)(r0 + 4 * i);
            float4 v1 = *(const float4*)(r1 + 4 * i);
            w0p[2*i] = pack2f(v0.x, v0.y); w0p[2*i+1] = pack2f(v0.z, v0.w);
            w1p[2*i] = pack2f(v1.x, v1.y); w1p[2*i+1] = pack2f(v1.z, v1.w);
        }
    }
    const float bias0 = b_ih[tid]       + b_hh[tid];
    const float bias1 = b_ih[tid + 512] + b_hh[tid + 512];
    const int   g4A   = (tid & 255) * 4 + ((tid < 256) ? 0 : 1);   // row tid -> gate i or f
    __syncthreads();

    unsigned short* outh = XPh + ((size_t)b * TT + (size_t)q * 128) * 1024;
    for (int tt = 0; tt < 128; ++tt) {
        const uint4* xr = (const uint4*)(xq + tt * 32);
        float a0 = bias0, a1 = bias1;
        float a2 = 0.f, a3 = 0.f, a4 = 0.f, a5 = 0.f, a6 = 0.f, a7 = 0.f;
#pragma unroll
        for (int i = 0; i < 8; ++i) {
            uint4 xv = xr[i];
            a0 = dot2(up(w0p[4*i]),   up(xv.x), a0);  a1 = dot2(up(w1p[4*i]),   up(xv.x), a1);
            a2 = dot2(up(w0p[4*i+1]), up(xv.y), a2);  a3 = dot2(up(w1p[4*i+1]), up(xv.y), a3);
            a4 = dot2(up(w0p[4*i+2]), up(xv.z), a4);  a5 = dot2(up(w1p[4*i+2]), up(xv.z), a5);
            a6 = dot2(up(w0p[4*i+3]), up(xv.w), a6);  a7 = dot2(up(w1p[4*i+3]), up(xv.w), a7);
        }
        const float gA = (a0 + a2) + (a4 + a6);   // row tid
        const float gB = (a1 + a3) + (a5 + a7);   // row tid+512
        outh[tt * 1024 + g4A]     = f2s(gA);
        outh[tt * 1024 + g4A + 2] = f2s(gB);      // row tid+512 = gate r+2 of same unit
    }
}

// ---------------- phase 2: recurrence ----------------
// LDS: wl4 uint4[18][512] (147456 B) | h16 _Float16[2][256] (1024 B)
__global__ void
__attribute__((amdgpu_flat_work_group_size(512, 512), amdgpu_waves_per_eu(2, 2)))
ntm_rec(const float* __restrict__ W_hh,
        const unsigned short* __restrict__ XPh_in,
        unsigned short* __restrict__ Hd_in,
        const unsigned int* __restrict__ WS_in)
{
    extern __shared__ char smem[];
    uint4*    wl4 = (uint4*)smem;                         // [18][512]
    _Float16* h16 = (_Float16*)(smem + 18 * 512 * 16);    // [2][256]

    const unsigned short* XPh = XPh_in ? XPh_in : (const unsigned short*)g_ntm_ws;
    unsigned short*       Hd  = Hd_in  ? Hd_in  : (unsigned short*)(g_ntm_ws + XP_BYTES);
    const uint4*          WSq = (const uint4*)(WS_in ? WS_in
                              : (const unsigned int*)(g_ntm_ws + XP_BYTES + HD_BYTES));

    const int tid = threadIdx.x;
    const int b   = blockIdx.x;
    const int u   = tid >> 1;        // hidden unit
    const int e   = tid & 1;         // 0: rows (i_u, f_u); 1: rows (g_u, o_u)

    // ---- weights: rows u+512e (gate 2e) and 256+u+512e (gate 2e+1) ----
    const float* r0 = W_hh + (size_t)(u + 512 * e) * 256;
    const float* r1 = W_hh + (size_t)(256 + u + 512 * e) * 256;

    // pairs 0..19 -> VGPRs (quads 0..4)
    f16x2 w0[20], w1[20];
#pragma unroll
    for (int p = 0; p < 20; ++p) {
        float2 va = *(const float2*)(r0 + 2 * p);
        float2 vb = *(const float2*)(r1 + 2 * p);
        w0[p] = f16x2{(_Float16)va.x, (_Float16)va.y};
        w1[p] = f16x2{(_Float16)vb.x, (_Float16)vb.y};
    }
    // pairs 20..55 -> LDS (quads 5..13): group 2j = rowA quad 5+j, 2j+1 = rowB
#pragma unroll
    for (int j = 0; j < 9; ++j) {
        const float* s0 = r0 + 40 + 8 * j;
        const float* s1 = r1 + 40 + 8 * j;
        wl4[(2 * j)     * 512 + tid] = make_uint4(pack2f(s0[0], s0[1]), pack2f(s0[2], s0[3]),
                                                  pack2f(s0[4], s0[5]), pack2f(s0[6], s0[7]));
        wl4[(2 * j + 1) * 512 + tid] = make_uint4(pack2f(s1[0], s1[1]), pack2f(s1[2], s1[3]),
                                                  pack2f(s1[4], s1[5]), pack2f(s1[6], s1[7]));
    }
    // pairs 56..127 streamed from WSq each step (packed by pack_kernel).

    if (tid < 64) ((uint4*)h16)[tid] = make_uint4(0u, 0u, 0u, 0u);   // both h buffers = 0
    float c_state = 0.f;
    __syncthreads();

    const unsigned int* xpb = (const unsigned int*)XPh + (size_t)b * TT * 512;
    uint4*              Hd4 = (uint4*)Hd + (size_t)b * TT * 32;

    unsigned int xpc = xpb[tid];                                     // t = 0

    for (int t = 0; t < TT; ++t) {
        const uint4* hq = (const uint4*)(h16 + (t & 1) * 256);
        unsigned int xpn = xpc;
        if (t + 1 < TT) xpn = xpb[(size_t)(t + 1) * 512 + tid];      // prefetch

        float a0 = 0.f, a1 = 0.f, a2 = 0.f, a3 = 0.f;

        // ---- STREAM tier first (quads 14..31): memory issued early ----
#pragma unroll
        for (int j = 0; j < 18; ++j) {
            const uint4 hv  = hq[14 + j];
            const uint4 wsa = WSq[(2 * j)     * 512 + tid];
            const uint4 wsb = WSq[(2 * j + 1) * 512 + tid];
            a0 = dot2(up(wsa.x), up(hv.x), a0);  a2 = dot2(up(wsb.x), up(hv.x), a2);
            a1 = dot2(up(wsa.y), up(hv.y), a1);  a3 = dot2(up(wsb.y), up(hv.y), a3);
            a0 = dot2(up(wsa.z), up(hv.z), a0);  a2 = dot2(up(wsb.z), up(hv.z), a2);
            a1 = dot2(up(wsa.w), up(hv.w), a1);  a3 = dot2(up(wsb.w), up(hv.w), a3);
        }
        // ---- LDS tier (quads 5..13) ----
#pragma unroll
        for (int j = 0; j < 9; ++j) {
            const uint4 hv  = hq[5 + j];
            const uint4 wv0 = wl4[(2 * j)     * 512 + tid];
            const uint4 wv1 = wl4[(2 * j + 1) * 512 + tid];
            a0 = dot2(up(wv0.x), up(hv.x), a0);  a2 = dot2(up(wv1.x), up(hv.x), a2);
            a1 = dot2(up(wv0.y), up(hv.y), a1);  a3 = dot2(up(wv1.y), up(hv.y), a3);
            a0 = dot2(up(wv0.z), up(hv.z), a0);  a2 = dot2(up(wv1.z), up(hv.z), a2);
            a1 = dot2(up(wv0.w), up(hv.w), a1);  a3 = dot2(up(wv1.w), up(hv.w), a3);
        }
        // ---- VGPR tier last (quads 0..4): pure VALU covers load tails ----
#pragma unroll
        for (int q = 0; q < 5; ++q) {
            const uint4 hv = hq[q];
            a0 = dot2(w0[4*q],   up(hv.x), a0);  a2 = dot2(w1[4*q],   up(hv.x), a2);
            a1 = dot2(w0[4*q+1], up(hv.y), a1);  a3 = dot2(w1[4*q+1], up(hv.y), a3);
            a0 = dot2(w0[4*q+2], up(hv.z), a0);  a2 = dot2(w1[4*q+2], up(hv.z), a2);
            a1 = dot2(w0[4*q+3], up(hv.w), a1);  a3 = dot2(w1[4*q+3], up(hv.w), a3);
        }

        // my two gates (+ x-projection incl. biases)
        const f16x2 xg = up(xpc);
        const float gM0 = (a0 + a1) + (float)xg.x;   // e=0: i_u ; e=1: g_u
        const float gM1 = (a2 + a3) + (float)xg.y;   // e=0: f_u ; e=1: o_u
        // exchange with lane^1 (other gate pair of the same unit)
        const float p0 = __shfl_xor(gM0, 1);
        const float p1 = __shfl_xor(gM1, 1);
        const float gi = e ? p0 : gM0;
        const float gf = e ? p1 : gM1;
        const float gg = e ? gM0 : p0;
        const float go = e ? gM1 : p1;
        // LSTM cell (redundant in both lanes of the pair; deterministic)
        c_state = sigf(gf) * c_state + sigf(gi) * tanhfast(gg);
        const float hn = sigf(go) * tanhfast(c_state);

        _Float16* hw = h16 + ((t + 1) & 1) * 256;
        if (!e) hw[u] = (_Float16)hn;
        __syncthreads();                                             // h_t published
        if (tid < 32) Hd4[(size_t)t * 32 + tid] = ((const uint4*)hw)[tid];
        xpc = xpn;
    }
}

// ---------------- phase 3: decode ----------------
// out[b,t,o] = b_dec[o] + H[b,t,:256] . W_dec[o,:256]
__global__ void __attribute__((amdgpu_flat_work_group_size(256, 256)))
dec_kernel(const unsigned short* __restrict__ Hd_in,
           const float* __restrict__ W_dec, const float* __restrict__ b_dec,
           float* __restrict__ out)
{
    const unsigned short* Hd = Hd_in ? Hd_in : (const unsigned short*)(g_ntm_ws + XP_BYTES);
    __shared__ unsigned int wdl[64 * 132];    // W_dec pairs, padded stride 132
    __shared__ uint4 ht[32 * 32];             // 32 t-rows x 256 f16

    const int tid = threadIdx.x;
    const int b = blockIdx.x >> 2, q = blockIdx.x & 3;

    for (int idx = tid; idx < 64 * 128; idx += 256) {
        const int o = idx >> 7, pp = idx & 127;
        wdl[o * 132 + pp] = pack2f(W_dec[(size_t)o * 384 + 2 * pp],
                                   W_dec[(size_t)o * 384 + 2 * pp + 1]);
    }
    const int o = tid & 63, tq = tid >> 6;
    const float bd = b_dec[o];
    const uint4* Hdb  = (const uint4*)Hd + ((size_t)b * TT + (size_t)q * 128) * 32;
    float*       outb = out + ((size_t)b * TT + (size_t)q * 128) * 64;

    for (int s = 0; s < 4; ++s) {
        __syncthreads();
#pragma unroll
        for (int i = 0; i < 4; ++i) {
            const int idx = tid + 256 * i;                 // 1024 uint4 = 32 rows
            ht[idx] = Hdb[s * 1024 + idx];
        }
        __syncthreads();

        float acc[8];
#pragma unroll
        for (int j = 0; j < 8; ++j) acc[j] = 0.f;

#pragma unroll
        for (int c = 0; c < 8; ++c) {                      // k-chunks of 32 slices
            uint4 w0, w1, w2, w3;
            {
                const unsigned int* wp = wdl + o * 132 + 16 * c;
                w0 = make_uint4(wp[0],  wp[1],  wp[2],  wp[3]);
                w1 = make_uint4(wp[4],  wp[5],  wp[6],  wp[7]);
                w2 = make_uint4(wp[8],  wp[9],  wp[10], wp[11]);
                w3 = make_uint4(wp[12], wp[13], wp[14], wp[15]);
            }
#pragma unroll
            for (int j = 0; j < 8; ++j) {
                const uint4* hr = &ht[(tq * 8 + j) * 32 + 4 * c];
                const uint4 h0 = hr[0], h1 = hr[1], h2 = hr[2], h3 = hr[3];
                float d = acc[j];
                d = dot2(up(w0.x), up(h0.x), d); d = dot2(up(w0.y), up(h0.y), d);
                d = dot2(up(w0.z), up(h0.z), d); d = dot2(up(w0.w), up(h0.w), d);
                d = dot2(up(w1.x), up(h1.x), d); d = dot2(up(w1.y), up(h1.y), d);
                d = dot2(up(w1.z), up(h1.z), d); d = dot2(up(w1.w), up(h1.w), d);
                d = dot2(up(w2.x), up(h2.x), d); d = dot2(up(w2.y), up(h2.y), d);
                d = dot2(up(w2.z), up(h2.z), d); d = dot2(up(w2.w), up(h2.w), d);
                d = dot2(up(w3.x), up(h3.x), d); d = dot2(up(w3.y), up(h3.y), d);
                d = dot2(up(w3.z), up(h3.z), d); d = dot2(up(w3.w), up(h3.w), d);
                acc[j] = d;
            }
        }
#pragma unroll
        for (int j = 0; j < 8; ++j)
            outb[(size_t)(s * 32 + tq * 8 + j) * 64 + o] = acc[j] + bd;
    }
}

extern "C" void kernel_launch(void* const* d_in, const int* in_sizes, int n_in,
                              void* d_out, int out_size, void* d_ws, size_t ws_size,
                              hipStream_t stream) {
    const float* x_seq = (const float*)d_in[0];
    const float* W_ih  = (const float*)d_in[1];
    const float* W_hh  = (const float*)d_in[2];
    const float* b_ih  = (const float*)d_in[3];
    const float* b_hh  = (const float*)d_in[4];
    // d_in[5..8] unused: mem == 0 forever
    const float* W_dec = (const float*)d_in[9];
    const float* b_dec = (const float*)d_in[10];
    float* out = (float*)d_out;

    unsigned short* XPh = nullptr;   // null -> kernels fall back to g_ntm_ws
    unsigned short* Hd  = nullptr;
    unsigned int*   WS  = nullptr;
    if (ws_size >= (size_t)XP_BYTES + HD_BYTES + WS_BYTES) {
        XPh = (unsigned short*)d_ws;
        Hd  = (unsigned short*)((unsigned char*)d_ws + XP_BYTES);
        WS  = (unsigned int*)((unsigned char*)d_ws + XP_BYTES + HD_BYTES);
    }

    hipLaunchKernelGGL(pack_kernel, dim3(36), dim3(512), 0, stream, W_hh, WS);
    hipLaunchKernelGGL(xproj_kernel, dim3(256), dim3(512), 0, stream,
                       x_seq, W_ih, b_ih, b_hh, XPh);

    const size_t smem_rec = (size_t)18 * 512 * 16 + 1024;   // 148480 B
    hipFuncSetAttribute((const void*)&ntm_rec,
                        hipFuncAttributeMaxDynamicSharedMemorySize, (int)smem_rec);
    hipLaunchKernelGGL(ntm_rec, dim3(NB), dim3(512), smem_rec, stream,
                       W_hh, XPh, Hd, WS);

    hipLaunchKernelGGL(dec_kernel, dim3(256), dim3(256), 0, stream,
                       Hd, W_dec, b_dec, out);
}